// Round 1
// baseline (187.216 us; speedup 1.0000x reference)
//
#include <hip/hip_runtime.h>
#include <math.h>

#define BB 4
#define NN 1024
#define FF 128
#define FOBS 32
#define DD 128

// ---------------------------------------------------------------- zero (f4)
__global__ __launch_bounds__(256) void zero_f4(float4* __restrict__ p, int n4) {
    int i = blockIdx.x * 256 + threadIdx.x;
    if (i < n4) p[i] = make_float4(0.f, 0.f, 0.f, 0.f);
}

// ---------------------------------------------------------------- adjacency
// A[b][i][j] = sigmoid(sum_f |h_i,f - h_j,f| * a_f),  diag forced to 0.
// 64x64 tile per block, 256 threads, each thread a 4x4 sub-tile.
__global__ __launch_bounds__(256) void adj_kernel(const float* __restrict__ X,
                                                  const float* __restrict__ a_link,
                                                  float* __restrict__ A) {
    int b = blockIdx.z, i0 = blockIdx.y * 64, j0 = blockIdx.x * 64;
    __shared__ float hi[64][FOBS + 1];   // +1 pad: row-stride 33 -> spread banks
    __shared__ float hj[64][FOBS + 1];
    __shared__ float av[FOBS];
    int tid = threadIdx.x;
    const float* Xb = X + (size_t)b * NN * FF;
#pragma unroll
    for (int l = 0; l < 8; l++) {
        int idx = l * 256 + tid;
        int r = idx >> 5, f = idx & 31;
        hi[r][f] = Xb[(size_t)(i0 + r) * FF + f];
        hj[r][f] = Xb[(size_t)(j0 + r) * FF + f];
    }
    if (tid < FOBS) av[tid] = a_link[tid];
    __syncthreads();

    int ty = tid >> 4, tx = tid & 15;
    int ir = ty * 4, jc = tx * 4;
    float acc[4][4] = {};
#pragma unroll
    for (int f = 0; f < FOBS; f++) {
        float a = av[f];
        float x[4], y[4];
#pragma unroll
        for (int r = 0; r < 4; r++) x[r] = hi[ir + r][f];
#pragma unroll
        for (int c = 0; c < 4; c++) y[c] = hj[jc + c][f];
#pragma unroll
        for (int r = 0; r < 4; r++)
#pragma unroll
            for (int c = 0; c < 4; c++)
                acc[r][c] += fabsf(x[r] - y[c]) * a;
    }
    float* Ab = A + (size_t)b * NN * NN;
#pragma unroll
    for (int r = 0; r < 4; r++) {
        int gi = i0 + ir + r;
        float vv[4];
#pragma unroll
        for (int c = 0; c < 4; c++) {
            int gj = j0 + jc + c;
            float sg = 1.f / (1.f + __expf(-acc[r][c]));
            vv[c] = (gi == gj) ? 0.f : sg;
        }
        *(float4*)&Ab[(size_t)gi * NN + (j0 + jc)] = make_float4(vv[0], vv[1], vv[2], vv[3]);
    }
}

// ---------------------------------------------------------------- dinv
// dinv[row] = rsqrt(1 + sum_j A[row][j])  (deterministic block reduction)
__global__ __launch_bounds__(256) void dinv_kernel(const float* __restrict__ A,
                                                   float* __restrict__ dinv) {
    int row = blockIdx.x;                    // flattened b*N+i
    const float* Ar = A + (size_t)row * NN;
    int tid = threadIdx.x;
    float4 v = *(const float4*)&Ar[tid * 4];
    float s = v.x + v.y + v.z + v.w;
#pragma unroll
    for (int off = 32; off; off >>= 1) s += __shfl_down(s, off);
    __shared__ float wsum[4];
    if ((tid & 63) == 0) wsum[tid >> 6] = s;
    __syncthreads();
    if (tid == 0) dinv[row] = rsqrtf(wsum[0] + wsum[1] + wsum[2] + wsum[3] + 1.f);
}

// ---------------------------------------------------------------- small GEMM
// t'[b][i][k] = dinv[i] * (In[b] @ W)[i][k]        (1024x128 @ 128x128)
__global__ __launch_bounds__(256) void gemm_w_kernel(const float* __restrict__ In,
                                                     const float* __restrict__ W,
                                                     const float* __restrict__ dinv,
                                                     float* __restrict__ Out) {
    int b = blockIdx.z;
    int i0 = blockIdx.x * 64;
    __shared__ float in_s[64][33];
    __shared__ float w_s[32][129];
    int tid = threadIdx.x;
    int ty = tid >> 4, tx = tid & 15;        // rows ty*4+r, cols c*16+tx
    const float* Inb = In + (size_t)b * NN * DD;
    float acc[4][8] = {};
    for (int kt = 0; kt < DD; kt += 32) {
#pragma unroll
        for (int l = 0; l < 8; l++) {
            int idx = l * 256 + tid; int r = idx >> 5, k = idx & 31;
            in_s[r][k] = Inb[(size_t)(i0 + r) * DD + kt + k];
        }
#pragma unroll
        for (int l = 0; l < 16; l++) {
            int idx = l * 256 + tid; int r = idx >> 7, k = idx & 127;
            w_s[r][k] = W[(size_t)(kt + r) * DD + k];
        }
        __syncthreads();
#pragma unroll
        for (int kk = 0; kk < 32; kk++) {
            float a[4], bb[8];
#pragma unroll
            for (int r = 0; r < 4; r++) a[r] = in_s[ty * 4 + r][kk];
#pragma unroll
            for (int c = 0; c < 8; c++) bb[c] = w_s[kk][c * 16 + tx];
#pragma unroll
            for (int r = 0; r < 4; r++)
#pragma unroll
                for (int c = 0; c < 8; c++) acc[r][c] += a[r] * bb[c];
        }
        __syncthreads();
    }
    float* Ob = Out + (size_t)b * NN * DD;
#pragma unroll
    for (int r = 0; r < 4; r++) {
        int gi = i0 + ty * 4 + r;
        float dv = dinv[b * NN + gi];
#pragma unroll
        for (int c = 0; c < 8; c++) Ob[(size_t)gi * DD + c * 16 + tx] = acc[r][c] * dv;
    }
}

// ---------------------------------------------------------------- big A-GEMM
// H[b][i][k] = dinv[i] * ( sum_j A[b][i][j]*T[b][j][k] + T[b][i][k] )
// 16 rows x 128 cols per block, K=1024 in tiles of 64.
template <int RELU>
__global__ __launch_bounds__(256) void gemm_a_kernel(const float* __restrict__ A,
                                                     const float* __restrict__ T,
                                                     const float* __restrict__ dinv,
                                                     float* __restrict__ H) {
    int b = blockIdx.z;
    int i0 = blockIdx.x * 16;
    __shared__ float a_s[16][65];
    __shared__ float t_s[64][128];
    int tid = threadIdx.x;
    int ty = tid >> 5, tx = tid & 31;        // rows ty*2+r (16), cols c*32+tx (128)
    const float* Ab = A + (size_t)b * NN * NN;
    const float* Tb = T + (size_t)b * NN * DD;
    float acc[2][4] = {};
    for (int kt = 0; kt < NN; kt += 64) {
        {   // stage A tile: 16x64 = 256 float4
            int r = tid >> 4, k4 = tid & 15;
            float4 v = *(const float4*)&Ab[(size_t)(i0 + r) * NN + kt + k4 * 4];
            a_s[r][k4 * 4 + 0] = v.x; a_s[r][k4 * 4 + 1] = v.y;
            a_s[r][k4 * 4 + 2] = v.z; a_s[r][k4 * 4 + 3] = v.w;
        }
#pragma unroll
        for (int l = 0; l < 8; l++) {        // stage T tile: 64x128 = 2048 float4
            int idx = l * 256 + tid; int r = idx >> 5, k4 = idx & 31;
            *(float4*)&t_s[r][k4 * 4] = *(const float4*)&Tb[(size_t)(kt + r) * DD + k4 * 4];
        }
        __syncthreads();
#pragma unroll
        for (int kk = 0; kk < 64; kk++) {
            float a0 = a_s[ty * 2 + 0][kk];
            float a1 = a_s[ty * 2 + 1][kk];
            float bb[4];
#pragma unroll
            for (int c = 0; c < 4; c++) bb[c] = t_s[kk][c * 32 + tx];
#pragma unroll
            for (int c = 0; c < 4; c++) { acc[0][c] += a0 * bb[c]; acc[1][c] += a1 * bb[c]; }
        }
        __syncthreads();
    }
    float* Hb = H + (size_t)b * NN * DD;
#pragma unroll
    for (int r = 0; r < 2; r++) {
        int gi = i0 + ty * 2 + r;
        float dv = dinv[b * NN + gi];
#pragma unroll
        for (int c = 0; c < 4; c++) {
            int col = c * 32 + tx;
            float v = (acc[r][c] + Tb[(size_t)gi * DD + col]) * dv;
            if (RELU) v = fmaxf(v, 0.f);
            Hb[(size_t)gi * DD + col] = v;
        }
    }
}

// ---------------------------------------------------------------- launcher
extern "C" void kernel_launch(void* const* d_in, const int* in_sizes, int n_in,
                              void* d_out, int out_size, void* d_ws, size_t ws_size,
                              hipStream_t stream) {
    const float* X      = (const float*)d_in[0];
    const float* a_link = (const float*)d_in[1];
    const float* W0     = (const float*)d_in[2];
    const float* W1     = (const float*)d_in[3];
    const float* W2     = (const float*)d_in[4];
    float* out = (float*)d_out;

    const size_t HND = (size_t)BB * NN * DD;     // 524288
    const size_t HNN = (size_t)BB * NN * NN;     // 4194304
    float* Hs = out;                             // [0, HND)
    float* As = out + HND;                       // [HND, HND+HNN)
    float* Xo = out + HND + HNN;                 // [.., +HND)
    float* Ds = out + 2 * HND + HNN;             // [.., +HNN)  -- also scratch

    float* tbuf = Ds;                            // t' : B*N*D
    float* hbuf = Ds + HND;                      // H  : B*N*D
    float* dinv = Ds + 2 * HND;                  // B*N

    adj_kernel<<<dim3(16, 16, BB), 256, 0, stream>>>(X, a_link, As);
    dinv_kernel<<<dim3(BB * NN), 256, 0, stream>>>(As, dinv);

    // hop 0: H = norm @ (X @ W0)
    gemm_w_kernel<<<dim3(16, 1, BB), 256, 0, stream>>>(X, W0, dinv, tbuf);
    gemm_a_kernel<0><<<dim3(64, 1, BB), 256, 0, stream>>>(As, tbuf, dinv, hbuf);
    // hop 1: H = norm @ (H @ W1)
    gemm_w_kernel<<<dim3(16, 1, BB), 256, 0, stream>>>(hbuf, W1, dinv, tbuf);
    gemm_a_kernel<0><<<dim3(64, 1, BB), 256, 0, stream>>>(As, tbuf, dinv, hbuf);
    // hop 2: H = relu(norm @ (H @ W2))  -> Hs output
    gemm_w_kernel<<<dim3(16, 1, BB), 256, 0, stream>>>(hbuf, W2, dinv, tbuf);
    gemm_a_kernel<1><<<dim3(64, 1, BB), 256, 0, stream>>>(As, tbuf, dinv, Hs);

    // Ds output must be zeros; scratch is dead now.
    zero_f4<<<dim3((int)(HNN / 4 / 256)), 256, 0, stream>>>((float4*)Ds, (int)(HNN / 4));
    // X passthrough output
    hipMemcpyAsync(Xo, X, HND * sizeof(float), hipMemcpyDeviceToDevice, stream);
}

// Round 2
// 88.162 us; speedup vs baseline: 2.1236x; 2.1236x over previous
//
#include <hip/hip_runtime.h>
#include <math.h>

#define BB 4
#define NN 1024
#define FF 128
#define DD 128
#define FOBS 32

typedef __attribute__((ext_vector_type(8))) short bfrag;   // 8 bf16 = 4 VGPR
typedef __attribute__((ext_vector_type(4))) float ffrag;   // 4 f32 acc
typedef __attribute__((ext_vector_type(4))) unsigned short us4;

__device__ __forceinline__ unsigned short f2bf(float x) {
    unsigned u = __builtin_bit_cast(unsigned, x);
    u += 0x7fffu + ((u >> 16) & 1u);              // RNE
    return (unsigned short)(u >> 16);
}
__device__ __forceinline__ float bf2f(unsigned short s) {
    unsigned u = (unsigned)s << 16;
    return __builtin_bit_cast(float, u);
}
__device__ __forceinline__ void gload16(const void* g, void* l) {
    __builtin_amdgcn_global_load_lds((const __attribute__((address_space(1))) unsigned*)g,
                                     (__attribute__((address_space(3))) unsigned*)l, 16, 0, 0);
}

// ---------------------------------------------------------------- zero (f4)
__global__ __launch_bounds__(256) void zero_f4(float4* __restrict__ p, int n4) {
    int i = blockIdx.x * 256 + threadIdx.x;
    if (i < n4) p[i] = make_float4(0.f, 0.f, 0.f, 0.f);
}

// ---------------------------------------------------------------- W^T casts
// Wt[m][f'][f] = W_m[f][f']  (bf16)
__global__ __launch_bounds__(128) void wt_kernel(const float* __restrict__ W0,
                                                 const float* __restrict__ W1,
                                                 const float* __restrict__ W2,
                                                 unsigned short* __restrict__ Wt) {
    int m = blockIdx.y;
    const float* W = (m == 0) ? W0 : (m == 1) ? W1 : W2;
    int fp = blockIdx.x;
    int f = threadIdx.x;
    Wt[((size_t)m * 128 + fp) * 128 + f] = f2bf(W[(size_t)f * 128 + fp]);
}

// ---------------------------------------------------------------- X -> bf16
__global__ __launch_bounds__(256) void xcast_kernel(const float* __restrict__ X,
                                                    unsigned short* __restrict__ Xbf) {
    int i = blockIdx.x * 256 + threadIdx.x;
    float4 v = *(const float4*)&X[(size_t)i * 4];
    us4 o; o[0] = f2bf(v.x); o[1] = f2bf(v.y); o[2] = f2bf(v.z); o[3] = f2bf(v.w);
    *(us4*)&Xbf[(size_t)i * 4] = o;
}

// ---------------------------------------------------------------- adjacency
// A[b][i][j] = sigmoid(sum_f |h_i,f - h_j,f| * a_f), diag 0. f32 out + bf16 copy.
__global__ __launch_bounds__(256) void adj_kernel(const float* __restrict__ X,
                                                  const float* __restrict__ a_link,
                                                  float* __restrict__ A,
                                                  unsigned short* __restrict__ Abf) {
    int b = blockIdx.z, i0 = blockIdx.y * 64, j0 = blockIdx.x * 64;
    __shared__ float hi[64][FOBS + 1];
    __shared__ float hj[64][FOBS + 1];
    __shared__ float av[FOBS];
    int tid = threadIdx.x;
    const float* Xb = X + (size_t)b * NN * FF;
#pragma unroll
    for (int l = 0; l < 8; l++) {
        int idx = l * 256 + tid;
        int r = idx >> 5, f = idx & 31;
        hi[r][f] = Xb[(size_t)(i0 + r) * FF + f];
        hj[r][f] = Xb[(size_t)(j0 + r) * FF + f];
    }
    if (tid < FOBS) av[tid] = a_link[tid];
    __syncthreads();

    int ty = tid >> 4, tx = tid & 15;
    int ir = ty * 4, jc = tx * 4;
    float acc[4][4] = {};
#pragma unroll
    for (int f = 0; f < FOBS; f++) {
        float a = av[f];
        float x[4], y[4];
#pragma unroll
        for (int r = 0; r < 4; r++) x[r] = hi[ir + r][f];
#pragma unroll
        for (int c = 0; c < 4; c++) y[c] = hj[jc + c][f];
#pragma unroll
        for (int r = 0; r < 4; r++)
#pragma unroll
            for (int c = 0; c < 4; c++)
                acc[r][c] += fabsf(x[r] - y[c]) * a;
    }
    float* Ab = A + (size_t)b * NN * NN;
    unsigned short* Abb = Abf + (size_t)b * NN * NN;
#pragma unroll
    for (int r = 0; r < 4; r++) {
        int gi = i0 + ir + r;
        float vv[4];
#pragma unroll
        for (int c = 0; c < 4; c++) {
            int gj = j0 + jc + c;
            float sg = 1.f / (1.f + __expf(-acc[r][c]));
            vv[c] = (gi == gj) ? 0.f : sg;
        }
        *(float4*)&Ab[(size_t)gi * NN + (j0 + jc)] = make_float4(vv[0], vv[1], vv[2], vv[3]);
        us4 o; o[0] = f2bf(vv[0]); o[1] = f2bf(vv[1]); o[2] = f2bf(vv[2]); o[3] = f2bf(vv[3]);
        *(us4*)&Abb[(size_t)gi * NN + (j0 + jc)] = o;
    }
}

// ---------------------------------------------------------------- dinv
__global__ __launch_bounds__(256) void dinv_kernel(const unsigned short* __restrict__ Abf,
                                                   float* __restrict__ dinv) {
    int row = blockIdx.x;                        // flattened b*N+i
    const unsigned short* Ar = Abf + (size_t)row * NN;
    int tid = threadIdx.x;
    us4 v = *(const us4*)&Ar[tid * 4];
    float s = bf2f(v[0]) + bf2f(v[1]) + bf2f(v[2]) + bf2f(v[3]);
#pragma unroll
    for (int off = 32; off; off >>= 1) s += __shfl_down(s, off);
    __shared__ float wsum[4];
    if ((tid & 63) == 0) wsum[tid >> 6] = s;
    __syncthreads();
    if (tid == 0) dinv[row] = rsqrtf(wsum[0] + wsum[1] + wsum[2] + wsum[3] + 1.f);
}

// ---------------------------------------------------------------- gemm_w (MFMA)
// Tt[b][f'][n] = dinv[n] * sum_f W[f][f'] * Hin[b][n][f]
// A-op = Wt[f'][f] (bf16, staged in LDS), B-op[f][n] = Hin[n][f] (node-major).
__global__ __launch_bounds__(256) void gemm_w_kernel(const unsigned short* __restrict__ Hin,
                                                     const unsigned short* __restrict__ Wt,
                                                     const float* __restrict__ dinv,
                                                     unsigned short* __restrict__ Tt) {
    int b = blockIdx.y;
    int n0 = blockIdx.x * 32;
    __shared__ unsigned short Wt_s[128 * 128];
    __shared__ unsigned short H_s[32 * 128];
    int tid = threadIdx.x;
    const unsigned short* Hb = Hin + (size_t)b * NN * DD;
#pragma unroll
    for (int p = 0; p < 8; p++) {                // Wt: 2048 x 16B chunks
        int c = p * 256 + tid;
        int row = c >> 4, kc = c & 15;
        gload16(Wt + (size_t)row * 128 + ((kc ^ (row & 7)) * 8), Wt_s + (size_t)c * 8);
    }
#pragma unroll
    for (int p = 0; p < 2; p++) {                // H tile: 512 x 16B chunks
        int c = p * 256 + tid;
        int row = c >> 4, kc = c & 15;
        gload16(Hb + (size_t)(n0 + row) * 128 + ((kc ^ (row & 7)) * 8), H_s + (size_t)c * 8);
    }
    __syncthreads();

    int w = tid >> 6, l = tid & 63, lr = l & 15, lg = l >> 4;
    ffrag acc[2][2] = {};
#pragma unroll
    for (int ks = 0; ks < 4; ks++) {
        int k0 = ks * 32 + lg * 8;
        bfrag a[2], bb[2];
#pragma unroll
        for (int rb = 0; rb < 2; rb++) {
            int row = w * 32 + rb * 16 + lr;
            int byt = (row * 256 + k0 * 2) ^ ((row & 7) << 4);
            a[rb] = *(const bfrag*)((const char*)Wt_s + byt);
        }
#pragma unroll
        for (int cb = 0; cb < 2; cb++) {
            int row = cb * 16 + lr;
            int byt = (row * 256 + k0 * 2) ^ ((row & 7) << 4);
            bb[cb] = *(const bfrag*)((const char*)H_s + byt);
        }
#pragma unroll
        for (int rb = 0; rb < 2; rb++)
#pragma unroll
            for (int cb = 0; cb < 2; cb++)
                acc[rb][cb] = __builtin_amdgcn_mfma_f32_16x16x32_bf16(a[rb], bb[cb], acc[rb][cb], 0, 0, 0);
    }
    unsigned short* Ttb = Tt + (size_t)b * DD * NN;
#pragma unroll
    for (int cb = 0; cb < 2; cb++) {
        int n = n0 + cb * 16 + lr;
        float dv = dinv[b * NN + n];
#pragma unroll
        for (int rb = 0; rb < 2; rb++)
#pragma unroll
            for (int r = 0; r < 4; r++) {
                int f = w * 32 + rb * 16 + lg * 4 + r;
                Ttb[(size_t)f * NN + n] = f2bf(acc[rb][cb][r] * dv);
            }
    }
}

// ---------------------------------------------------------------- gemm_a (MFMA)
// D[f'][n] = sum_k Tt[f'][k] * A[k][n]   (A symmetric: read A[n][k] contiguous)
// H[n][f'] = dinv[n] * (D + Tt[f'][n]), relu+f32 on last hop.
template <int LAST>
__global__ __launch_bounds__(256) void gemm_a_kernel(const unsigned short* __restrict__ Abf,
                                                     const unsigned short* __restrict__ Tt,
                                                     const float* __restrict__ dinv,
                                                     unsigned short* __restrict__ Hout,
                                                     float* __restrict__ HoutF) {
    int b = blockIdx.y;
    int n0 = blockIdx.x * 32;
    __shared__ unsigned short T_s[2][128 * 64];
    __shared__ unsigned short A_s[2][32 * 64];
    int tid = threadIdx.x;
    const unsigned short* Ttb = Tt + (size_t)b * DD * NN;
    const unsigned short* Ab = Abf + (size_t)b * NN * NN;

    auto stage = [&](int buf, int kt) {
#pragma unroll
        for (int p = 0; p < 4; p++) {            // Tt tile 128x64: 1024 chunks
            int c = p * 256 + tid;
            int row = c >> 3, kc = c & 7;
            gload16(Ttb + (size_t)row * NN + kt + ((kc ^ (row & 7)) * 8), &T_s[buf][(size_t)c * 8]);
        }
        {                                        // A tile 32x64: 256 chunks
            int c = tid;
            int row = c >> 3, kc = c & 7;
            gload16(Ab + (size_t)(n0 + row) * NN + kt + ((kc ^ (row & 7)) * 8), &A_s[buf][(size_t)c * 8]);
        }
    };
    stage(0, 0);

    int w = tid >> 6, l = tid & 63, lr = l & 15, lg = l >> 4;
    ffrag acc[2][2] = {};
    for (int t = 0; t < 16; t++) {
        int cur = t & 1;
        __syncthreads();                         // stage(cur) landed; prev reads done
        if (t < 15) stage(cur ^ 1, (t + 1) * 64);
#pragma unroll
        for (int ks = 0; ks < 2; ks++) {
            int k0 = ks * 32 + lg * 8;
            bfrag a[2], bb[2];
#pragma unroll
            for (int rb = 0; rb < 2; rb++) {
                int row = w * 32 + rb * 16 + lr;
                int byt = (row * 128 + k0 * 2) ^ ((row & 7) << 4);
                a[rb] = *(const bfrag*)((const char*)&T_s[cur][0] + byt);
            }
#pragma unroll
            for (int cb = 0; cb < 2; cb++) {
                int row = cb * 16 + lr;
                int byt = (row * 128 + k0 * 2) ^ ((row & 7) << 4);
                bb[cb] = *(const bfrag*)((const char*)&A_s[cur][0] + byt);
            }
#pragma unroll
            for (int rb = 0; rb < 2; rb++)
#pragma unroll
                for (int cb = 0; cb < 2; cb++)
                    acc[rb][cb] = __builtin_amdgcn_mfma_f32_16x16x32_bf16(a[rb], bb[cb], acc[rb][cb], 0, 0, 0);
        }
    }

#pragma unroll
    for (int cb = 0; cb < 2; cb++) {
        int n = n0 + cb * 16 + lr;
        float dv = dinv[b * NN + n];
#pragma unroll
        for (int rb = 0; rb < 2; rb++) {
            int fb = w * 32 + rb * 16 + lg * 4;
            float v[4];
#pragma unroll
            for (int r = 0; r < 4; r++) {
                float idv = bf2f(Ttb[(size_t)(fb + r) * NN + n]);   // identity term
                v[r] = (acc[rb][cb][r] + idv) * dv;
                if (LAST) v[r] = fmaxf(v[r], 0.f);
            }
            if (LAST) {
                *(float4*)&HoutF[((size_t)b * NN + n) * DD + fb] = make_float4(v[0], v[1], v[2], v[3]);
            } else {
                us4 o; o[0] = f2bf(v[0]); o[1] = f2bf(v[1]); o[2] = f2bf(v[2]); o[3] = f2bf(v[3]);
                *(us4*)&Hout[((size_t)b * NN + n) * DD + fb] = o;
            }
        }
    }
}

// ---------------------------------------------------------------- launcher
extern "C" void kernel_launch(void* const* d_in, const int* in_sizes, int n_in,
                              void* d_out, int out_size, void* d_ws, size_t ws_size,
                              hipStream_t stream) {
    const float* X      = (const float*)d_in[0];
    const float* a_link = (const float*)d_in[1];
    const float* W0     = (const float*)d_in[2];
    const float* W1     = (const float*)d_in[3];
    const float* W2     = (const float*)d_in[4];
    float* out = (float*)d_out;

    const size_t HND = (size_t)BB * NN * DD;     // 524288
    const size_t HNN = (size_t)BB * NN * NN;     // 4194304
    float* Hs = out;
    float* As = out + HND;
    float* Xo = out + HND + HNN;
    float* Ds = out + 2 * HND + HNN;             // scratch region (zeroed at end)

    unsigned short* Abf  = (unsigned short*)Ds;                        // 4194304 bf16
    unsigned short* Xbf  = (unsigned short*)(Ds + 2097152);            // 524288 bf16
    unsigned short* Tt   = (unsigned short*)(Ds + 2097152 + 262144);   // 524288 bf16
    unsigned short* Hbf  = (unsigned short*)(Ds + 2097152 + 524288);   // 524288 bf16
    unsigned short* Wt   = (unsigned short*)(Ds + 2097152 + 786432);   // 49152 bf16
    float* dinvp         = Ds + 2097152 + 786432 + 24576;              // 4096 f32

    wt_kernel<<<dim3(128, 3), 128, 0, stream>>>(W0, W1, W2, Wt);
    xcast_kernel<<<dim3(512), 256, 0, stream>>>(X, Xbf);
    adj_kernel<<<dim3(16, 16, BB), 256, 0, stream>>>(X, a_link, As, Abf);
    dinv_kernel<<<dim3(BB * NN), 256, 0, stream>>>(Abf, dinvp);

    gemm_w_kernel<<<dim3(32, BB), 256, 0, stream>>>(Xbf, Wt, dinvp, Tt);
    gemm_a_kernel<0><<<dim3(32, BB), 256, 0, stream>>>(Abf, Tt, dinvp, Hbf, nullptr);
    gemm_w_kernel<<<dim3(32, BB), 256, 0, stream>>>(Hbf, Wt + 16384, dinvp, Tt);
    gemm_a_kernel<0><<<dim3(32, BB), 256, 0, stream>>>(Abf, Tt, dinvp, Hbf, nullptr);
    gemm_w_kernel<<<dim3(32, BB), 256, 0, stream>>>(Hbf, Wt + 32768, dinvp, Tt);
    gemm_a_kernel<1><<<dim3(32, BB), 256, 0, stream>>>(Abf, Tt, dinvp, nullptr, Hs);

    zero_f4<<<dim3(4096), 256, 0, stream>>>((float4*)Ds, (int)(HNN / 4));
    hipMemcpyAsync(Xo, X, HND * sizeof(float), hipMemcpyDeviceToDevice, stream);
}

// Round 3
// 67.024 us; speedup vs baseline: 2.7933x; 1.3154x over previous
//
#include <hip/hip_runtime.h>
#include <math.h>

#define BB 4
#define NN 1024
#define FF 128
#define DD 128
#define FOBS 32

typedef __attribute__((ext_vector_type(8))) short bfrag;   // 8 bf16 = 4 VGPR
typedef __attribute__((ext_vector_type(4))) float ffrag;   // 4 f32 acc
typedef __attribute__((ext_vector_type(4))) unsigned short us4;

__device__ __forceinline__ unsigned short f2bf(float x) {
    unsigned u = __builtin_bit_cast(unsigned, x);
    u += 0x7fffu + ((u >> 16) & 1u);              // RNE
    return (unsigned short)(u >> 16);
}
__device__ __forceinline__ float bf2f(unsigned short s) {
    unsigned u = (unsigned)s << 16;
    return __builtin_bit_cast(float, u);
}
__device__ __forceinline__ void gload16(const void* g, void* l) {
    __builtin_amdgcn_global_load_lds((const __attribute__((address_space(1))) unsigned*)g,
                                     (__attribute__((address_space(3))) unsigned*)l, 16, 0, 0);
}
// dinv[n0..n0+31] from 16 f32 partial row-sums each; deterministic fixed-order tree.
__device__ __forceinline__ void compute_dinv(const float* __restrict__ Pp, int b, int n0,
                                             int tid, float* dinv_s) {
    int r = tid >> 3, p = tid & 7;                // 256 thr -> 32 rows x 8 lanes
    float2 v = *(const float2*)&Pp[((size_t)b * NN + n0 + r) * 16 + p * 2];
    float s = v.x + v.y;
    s += __shfl_xor(s, 1);
    s += __shfl_xor(s, 2);
    s += __shfl_xor(s, 4);
    if (p == 0) dinv_s[r] = rsqrtf(1.f + s);
}

// ---------------------------------------------------------------- zero (f4)
__global__ __launch_bounds__(256) void zero_f4(float4* __restrict__ p, int n4) {
    int i = blockIdx.x * 256 + threadIdx.x;
    if (i < n4) p[i] = make_float4(0.f, 0.f, 0.f, 0.f);
}

// ---------------------------------------------------------------- adjacency (+prep +partials +Xo)
__global__ __launch_bounds__(256) void adj_kernel(const float* __restrict__ X,
                                                  const float* __restrict__ a_link,
                                                  const float* __restrict__ W0,
                                                  const float* __restrict__ W1,
                                                  const float* __restrict__ W2,
                                                  float* __restrict__ A,
                                                  unsigned short* __restrict__ Abf,
                                                  unsigned short* __restrict__ Xbf,
                                                  unsigned short* __restrict__ Wt,
                                                  float* __restrict__ Pp,
                                                  float* __restrict__ Xo) {
    int tid = threadIdx.x;
    if (blockIdx.z == 4) {                        // prep: Wt casts + X->bf16
        int q = (blockIdx.y * 16 + blockIdx.x) * 256 + tid;   // 0..65535
        if (q < 49152) {
            int m = q >> 14, rem = q & 16383, fp = rem >> 7, f = rem & 127;
            const float* W = (m == 0) ? W0 : (m == 1) ? W1 : W2;
            Wt[q] = f2bf(W[(size_t)f * 128 + fp]);
        } else {
            int u = q - 49152;                    // 0..16383, 8 float4 each
#pragma unroll
            for (int p = 0; p < 8; p++) {
                size_t i4 = (size_t)u + (size_t)p * 16384;
                float4 v = *(const float4*)&X[i4 * 4];
                us4 o; o[0] = f2bf(v.x); o[1] = f2bf(v.y); o[2] = f2bf(v.z); o[3] = f2bf(v.w);
                *(us4*)&Xbf[i4 * 4] = o;
            }
        }
        return;
    }
    int b = blockIdx.z, i0 = blockIdx.y * 64, j0 = blockIdx.x * 64;
    __shared__ float hi[64][FOBS + 1];
    __shared__ float hj[64][FOBS + 1];
    __shared__ float av[FOBS];
    __shared__ float part_s[64][16];
    const float* Xb = X + (size_t)b * NN * FF;
    if (j0 == 0) {                                // Xo passthrough for this row-panel
#pragma unroll
        for (int p = 0; p < 8; p++) {
            int c = p * 256 + tid, r = c >> 5, qq = c & 31;
            *(float4*)&Xo[((size_t)b * NN + i0 + r) * FF + qq * 4] =
                *(const float4*)&Xb[(size_t)(i0 + r) * FF + qq * 4];
        }
    }
#pragma unroll
    for (int l = 0; l < 8; l++) {
        int idx = l * 256 + tid;
        int r = idx >> 5, f = idx & 31;
        hi[r][f] = Xb[(size_t)(i0 + r) * FF + f];
        hj[r][f] = Xb[(size_t)(j0 + r) * FF + f];
    }
    if (tid < FOBS) av[tid] = a_link[tid];
    __syncthreads();

    int ty = tid >> 4, tx = tid & 15;
    int ir = ty * 4, jc = tx * 4;
    float acc[4][4] = {};
#pragma unroll
    for (int f = 0; f < FOBS; f++) {
        float a = av[f];
        float x[4], y[4];
#pragma unroll
        for (int r = 0; r < 4; r++) x[r] = hi[ir + r][f];
#pragma unroll
        for (int c = 0; c < 4; c++) y[c] = hj[jc + c][f];
#pragma unroll
        for (int r = 0; r < 4; r++)
#pragma unroll
            for (int c = 0; c < 4; c++)
                acc[r][c] += fabsf(x[r] - y[c]) * a;
    }
    float* Ab = A + (size_t)b * NN * NN;
    unsigned short* Abb = Abf + (size_t)b * NN * NN;
#pragma unroll
    for (int r = 0; r < 4; r++) {
        int gi = i0 + ir + r;
        float vv[4];
        float rs = 0.f;
#pragma unroll
        for (int c = 0; c < 4; c++) {
            int gj = j0 + jc + c;
            float sg = 1.f / (1.f + __expf(-acc[r][c]));
            vv[c] = (gi == gj) ? 0.f : sg;
            rs += vv[c];
        }
        *(float4*)&Ab[(size_t)gi * NN + (j0 + jc)] = make_float4(vv[0], vv[1], vv[2], vv[3]);
        us4 o; o[0] = f2bf(vv[0]); o[1] = f2bf(vv[1]); o[2] = f2bf(vv[2]); o[3] = f2bf(vv[3]);
        *(us4*)&Abb[(size_t)gi * NN + (j0 + jc)] = o;
        part_s[ir + r][tx] = rs;                  // each (row, tx) slot written once
    }
    __syncthreads();
    if (tid < 64) {                               // 16 partials -> one f32 per row
        float s = 0.f;
#pragma unroll
        for (int k = 0; k < 16; k++) s += part_s[tid][k];
        Pp[((size_t)b * NN + i0 + tid) * 16 + blockIdx.x] = s;
    }
}

// ---------------------------------------------------------------- gw0 (MFMA)
// Tt[b][f'][n] = dinv[n] * sum_f Wt0[f'][f] * Xbf[b][n][f]
__global__ __launch_bounds__(256) void gw0_kernel(const unsigned short* __restrict__ Xbf,
                                                  const unsigned short* __restrict__ Wt0,
                                                  const float* __restrict__ Pp,
                                                  unsigned short* __restrict__ TtOut) {
    int b = blockIdx.y;
    int n0 = blockIdx.x * 32;
    __shared__ unsigned short Wt_s[128 * 128];
    __shared__ unsigned short H_s[32 * 128];
    __shared__ float dinv_s[32];
    int tid = threadIdx.x;
    compute_dinv(Pp, b, n0, tid, dinv_s);
    const unsigned short* Hb = Xbf + (size_t)b * NN * DD;
#pragma unroll
    for (int p = 0; p < 8; p++) {
        int c = p * 256 + tid, row = c >> 4, kc = c & 15;
        gload16(Wt0 + (size_t)row * 128 + ((kc ^ (row & 7)) * 8), Wt_s + (size_t)c * 8);
    }
#pragma unroll
    for (int p = 0; p < 2; p++) {
        int c = p * 256 + tid, row = c >> 4, kc = c & 15;
        gload16(Hb + (size_t)(n0 + row) * 128 + ((kc ^ (row & 7)) * 8), H_s + (size_t)c * 8);
    }
    __syncthreads();

    int w = tid >> 6, l = tid & 63, lr = l & 15, lg = l >> 4;
    ffrag acc[2][2] = {};
#pragma unroll
    for (int ks = 0; ks < 4; ks++) {
        int k0 = ks * 32 + lg * 8;
        bfrag a[2], bb[2];
#pragma unroll
        for (int rb = 0; rb < 2; rb++) {
            int row = w * 32 + rb * 16 + lr;
            int byt = (row * 256 + k0 * 2) ^ ((row & 7) << 4);
            a[rb] = *(const bfrag*)((const char*)Wt_s + byt);
        }
#pragma unroll
        for (int cb = 0; cb < 2; cb++) {
            int row = cb * 16 + lr;
            int byt = (row * 256 + k0 * 2) ^ ((row & 7) << 4);
            bb[cb] = *(const bfrag*)((const char*)H_s + byt);
        }
#pragma unroll
        for (int rb = 0; rb < 2; rb++)
#pragma unroll
            for (int cb = 0; cb < 2; cb++)
                acc[rb][cb] = __builtin_amdgcn_mfma_f32_16x16x32_bf16(a[rb], bb[cb], acc[rb][cb], 0, 0, 0);
    }
    unsigned short* Ttb = TtOut + (size_t)b * DD * NN;
#pragma unroll
    for (int cb = 0; cb < 2; cb++) {
        int nl = cb * 16 + lr;
        float dv = dinv_s[nl];
#pragma unroll
        for (int rb = 0; rb < 2; rb++)
#pragma unroll
            for (int r = 0; r < 4; r++) {
                int f = w * 32 + rb * 16 + lg * 4 + r;
                Ttb[(size_t)f * NN + n0 + nl] = f2bf(acc[rb][cb][r] * dv);
            }
    }
}

// ---------------------------------------------------------------- ga (MFMA, depth-3 pipeline)
// Dacc[f][n] = sum_k Tt[f][k] * A[k][n] (A symmetric -> read A rows contiguous)
// H[n][f] = dinv[n]*(Dacc + Tt[f][n]).
// MODE 0: TtN[f2][n] = dinv[n] * sum_f WtN[f2][f]*H[n][f]   (fused next-hop W-GEMM)
// MODE 1: Hs[n][f] = relu(H) as f32.
template <int MODE>
__global__ __launch_bounds__(256) void ga_kernel(const unsigned short* __restrict__ Abf,
                                                 const unsigned short* __restrict__ Tt,
                                                 const unsigned short* __restrict__ WtN,
                                                 const float* __restrict__ Pp,
                                                 unsigned short* __restrict__ TtN,
                                                 float* __restrict__ HsF) {
    int b = blockIdx.y, n0 = blockIdx.x * 32;
    __shared__ unsigned short T_s[3 * 128 * 64];
    __shared__ unsigned short A_s[3 * 32 * 64];
    __shared__ unsigned short W_s[MODE == 0 ? 128 * 128 : 64];
    __shared__ float dinv_s[32];
    int tid = threadIdx.x;
    const unsigned short* Ttb = Tt + (size_t)b * DD * NN;
    const unsigned short* Ab = Abf + (size_t)b * NN * NN;

    compute_dinv(Pp, b, n0, tid, dinv_s);         // fully drains its own tiny load

    if (MODE == 0) {                              // W for fused epilogue: issued first
#pragma unroll
        for (int p = 0; p < 8; p++) {
            int c = p * 256 + tid, row = c >> 4, kc = c & 15;
            gload16(WtN + (size_t)row * 128 + ((kc ^ (row & 7)) * 8), W_s + (size_t)c * 8);
        }
    }
    auto stageT = [&](int buf, int kt) {          // 5 gload16 per thread
#pragma unroll
        for (int p = 0; p < 4; p++) {
            int c = p * 256 + tid, row = c >> 3, kc = c & 7;
            gload16(Ttb + (size_t)row * NN + kt + ((kc ^ (row & 7)) * 8),
                    T_s + (size_t)buf * (128 * 64) + (size_t)c * 8);
        }
        int c = tid, row = c >> 3, kc = c & 7;
        gload16(Ab + (size_t)(n0 + row) * NN + kt + ((kc ^ (row & 7)) * 8),
                A_s + (size_t)buf * (32 * 64) + (size_t)c * 8);
    };
    stageT(0, 0);
    stageT(1, 64);

    int w = tid >> 6, l = tid & 63, lr = l & 15, lg = l >> 4;
    ffrag acc[2][2] = {};
    int cur = 0, sb = 2;
    for (int t = 0; t < 16; t++) {
        if (t <= 13) stageT(sb, (t + 2) * 64);
        if (t < 14)       asm volatile("s_waitcnt vmcnt(10)" ::: "memory");
        else if (t == 14) asm volatile("s_waitcnt vmcnt(5)"  ::: "memory");
        else              asm volatile("s_waitcnt vmcnt(0)"  ::: "memory");
        __builtin_amdgcn_s_barrier();
        asm volatile("" ::: "memory");
        const unsigned short* Tc = T_s + (size_t)cur * (128 * 64);
        const unsigned short* Ac = A_s + (size_t)cur * (32 * 64);
#pragma unroll
        for (int ks = 0; ks < 2; ks++) {
            int k0 = ks * 32 + lg * 8;
            bfrag a[2], bb[2];
#pragma unroll
            for (int rb = 0; rb < 2; rb++) {
                int row = w * 32 + rb * 16 + lr;
                int byt = (row * 128 + k0 * 2) ^ ((row & 7) << 4);
                a[rb] = *(const bfrag*)((const char*)Tc + byt);
            }
#pragma unroll
            for (int cb = 0; cb < 2; cb++) {
                int row = cb * 16 + lr;
                int byt = (row * 128 + k0 * 2) ^ ((row & 7) << 4);
                bb[cb] = *(const bfrag*)((const char*)Ac + byt);
            }
#pragma unroll
            for (int rb = 0; rb < 2; rb++)
#pragma unroll
                for (int cb = 0; cb < 2; cb++)
                    acc[rb][cb] = __builtin_amdgcn_mfma_f32_16x16x32_bf16(a[rb], bb[cb], acc[rb][cb], 0, 0, 0);
        }
        asm volatile("s_waitcnt lgkmcnt(0)" ::: "memory");
        __builtin_amdgcn_s_barrier();             // all reads of buf done before overwrite
        cur = (cur == 2) ? 0 : cur + 1;
        sb = (sb == 2) ? 0 : sb + 1;
    }

    if (MODE == 1) {                              // final: relu, f32, node-major
#pragma unroll
        for (int cb = 0; cb < 2; cb++) {
            int nl = cb * 16 + lr;
            float dv = dinv_s[nl];
#pragma unroll
            for (int rb = 0; rb < 2; rb++) {
                int f0 = w * 32 + rb * 16 + lg * 4;
                float v[4];
#pragma unroll
                for (int r = 0; r < 4; r++) {
                    float idv = bf2f(Ttb[(size_t)(f0 + r) * NN + n0 + nl]);
                    v[r] = fmaxf((acc[rb][cb][r] + idv) * dv, 0.f);
                }
                *(float4*)&HsF[((size_t)b * NN + n0 + nl) * DD + f0] = make_float4(v[0], v[1], v[2], v[3]);
            }
        }
        return;
    }
    // MODE 0: H -> LDS (reuse T_s buffer 0; all pipeline reads done), then @ WtN
    unsigned short* H_s = T_s;                    // [32][128] swizzled, row stride 256B
#pragma unroll
    for (int cb = 0; cb < 2; cb++) {
        int nl = cb * 16 + lr;
        float dv = dinv_s[nl];
#pragma unroll
        for (int rb = 0; rb < 2; rb++) {
            int f0 = w * 32 + rb * 16 + lg * 4;
            us4 o;
#pragma unroll
            for (int r = 0; r < 4; r++) {
                float idv = bf2f(Ttb[(size_t)(f0 + r) * NN + n0 + nl]);
                o[r] = f2bf((acc[rb][cb][r] + idv) * dv);
            }
            int byt = (nl * 256 + f0 * 2) ^ ((nl & 7) << 4);
            *(us4*)((char*)H_s + byt) = o;
        }
    }
    __syncthreads();
    ffrag acc2[2][2] = {};
#pragma unroll
    for (int ks = 0; ks < 4; ks++) {
        int k0 = ks * 32 + lg * 8;
        bfrag a2[2], b2[2];
#pragma unroll
        for (int rb = 0; rb < 2; rb++) {
            int row = w * 32 + rb * 16 + lr;
            int byt = (row * 256 + k0 * 2) ^ ((row & 7) << 4);
            a2[rb] = *(const bfrag*)((const char*)W_s + byt);
        }
#pragma unroll
        for (int cb = 0; cb < 2; cb++) {
            int row = cb * 16 + lr;
            int byt = (row * 256 + k0 * 2) ^ ((row & 7) << 4);
            b2[cb] = *(const bfrag*)((const char*)H_s + byt);
        }
#pragma unroll
        for (int rb = 0; rb < 2; rb++)
#pragma unroll
            for (int cb = 0; cb < 2; cb++)
                acc2[rb][cb] = __builtin_amdgcn_mfma_f32_16x16x32_bf16(a2[rb], b2[cb], acc2[rb][cb], 0, 0, 0);
    }
    unsigned short* TtNb = TtN + (size_t)b * DD * NN;
#pragma unroll
    for (int cb = 0; cb < 2; cb++) {
        int nl = cb * 16 + lr;
        float dv = dinv_s[nl];
#pragma unroll
        for (int rb = 0; rb < 2; rb++)
#pragma unroll
            for (int r = 0; r < 4; r++) {
                int f2 = w * 32 + rb * 16 + lg * 4 + r;
                TtNb[(size_t)f2 * NN + n0 + nl] = f2bf(acc2[rb][cb][r] * dv);
            }
    }
}

// ---------------------------------------------------------------- launcher
extern "C" void kernel_launch(void* const* d_in, const int* in_sizes, int n_in,
                              void* d_out, int out_size, void* d_ws, size_t ws_size,
                              hipStream_t stream) {
    const float* X      = (const float*)d_in[0];
    const float* a_link = (const float*)d_in[1];
    const float* W0     = (const float*)d_in[2];
    const float* W1     = (const float*)d_in[3];
    const float* W2     = (const float*)d_in[4];
    float* out = (float*)d_out;

    const size_t HND = (size_t)BB * NN * DD;     // 524288
    const size_t HNN = (size_t)BB * NN * NN;     // 4194304
    float* Hs = out;
    float* As = out + HND;
    float* Xo = out + HND + HNN;
    float* Ds = out + 2 * HND + HNN;             // scratch region, zeroed at end

    unsigned short* Abf = (unsigned short*)Ds;                  // 2,097,152 fl
    unsigned short* Xbf = (unsigned short*)(Ds + 2097152);      //   262,144 fl
    unsigned short* TtA = (unsigned short*)(Ds + 2359296);      //   262,144 fl
    unsigned short* TtB = (unsigned short*)(Ds + 2621440);      //   262,144 fl
    unsigned short* Wt  = (unsigned short*)(Ds + 2883584);      //    24,576 fl
    float* Pp           = Ds + 2908160;                         //    65,536 fl

    adj_kernel<<<dim3(16, 16, 5), 256, 0, stream>>>(X, a_link, W0, W1, W2,
                                                    As, Abf, Xbf, Wt, Pp, Xo);
    gw0_kernel<<<dim3(32, BB), 256, 0, stream>>>(Xbf, Wt, Pp, TtA);
    ga_kernel<0><<<dim3(32, BB), 256, 0, stream>>>(Abf, TtA, Wt + 16384, Pp, TtB, nullptr);
    ga_kernel<0><<<dim3(32, BB), 256, 0, stream>>>(Abf, TtB, Wt + 32768, Pp, TtA, nullptr);
    ga_kernel<1><<<dim3(32, BB), 256, 0, stream>>>(Abf, TtA, nullptr, Pp, nullptr, Hs);
    zero_f4<<<dim3(4096), 256, 0, stream>>>((float4*)Ds, (int)(HNN / 4));
}

// Round 5
// 48.502 us; speedup vs baseline: 3.8599x; 1.3819x over previous
//
#include <hip/hip_runtime.h>
#include <math.h>

#define BB 4
#define NN 1024
#define FF 128
#define DD 128
#define FOBS 32

typedef __attribute__((ext_vector_type(8))) short bfrag;   // 8 bf16 = 4 VGPR
typedef __attribute__((ext_vector_type(4))) float ffrag;   // 4 f32 acc
typedef __attribute__((ext_vector_type(4))) unsigned short us4;

__device__ __forceinline__ unsigned short f2bf(float x) {
    unsigned u = __builtin_bit_cast(unsigned, x);
    u += 0x7fffu + ((u >> 16) & 1u);              // RNE
    return (unsigned short)(u >> 16);
}
__device__ __forceinline__ float bf2f(unsigned short s) {
    unsigned u = (unsigned)s << 16;
    return __builtin_bit_cast(float, u);
}
__device__ __forceinline__ void gload16(const void* g, void* l) {
    __builtin_amdgcn_global_load_lds((const __attribute__((address_space(1))) unsigned*)g,
                                     (__attribute__((address_space(3))) unsigned*)l, 16, 0, 0);
}
// dinv for 16 rows from 16 f32 partials each; deterministic fixed-order reduce.
__device__ __forceinline__ void compute_dinv16(const float* __restrict__ Pp, int b, int n0,
                                               int tid, float* dinv_s) {
    int r = tid >> 4, p = tid & 15;               // 256 thr -> 16 rows x 16 lanes
    float s = Pp[((size_t)b * NN + n0 + r) * 16 + p];
    s += __shfl_xor(s, 1);
    s += __shfl_xor(s, 2);
    s += __shfl_xor(s, 4);
    s += __shfl_xor(s, 8);
    if (p == 0) dinv_s[r] = rsqrtf(1.f + s);
}

// ---------------------------------------------------------------- zero (f4)  (fallback path)
__global__ __launch_bounds__(256) void zero_f4(float4* __restrict__ p, int n4) {
    int i = blockIdx.x * 256 + threadIdx.x;
    if (i < n4) p[i] = make_float4(0.f, 0.f, 0.f, 0.f);
}

// ---------------------------------------------------------------- adjacency (+prep +partials +Xo +Ds-zero)
__global__ __launch_bounds__(256) void adj_kernel(const float* __restrict__ X,
                                                  const float* __restrict__ a_link,
                                                  const float* __restrict__ W0,
                                                  const float* __restrict__ W1,
                                                  const float* __restrict__ W2,
                                                  float* __restrict__ A,
                                                  unsigned short* __restrict__ Abf,
                                                  unsigned short* __restrict__ Xbf,
                                                  unsigned short* __restrict__ Wt,
                                                  float* __restrict__ Pp,
                                                  float* __restrict__ Xo,
                                                  float* __restrict__ Zd) {
    int tid = threadIdx.x;
    if (blockIdx.z == 5) {                        // Ds-zero layer (only when scratch = d_ws)
        if (Zd) {
            int q = blockIdx.y * 16 + blockIdx.x; // 0..255
            float4* Z = (float4*)Zd;
#pragma unroll
            for (int p = 0; p < 16; p++)
                Z[(size_t)q * 4096 + p * 256 + tid] = make_float4(0.f, 0.f, 0.f, 0.f);
        }
        return;
    }
    if (blockIdx.z == 4) {                        // prep: Wt casts + X->bf16
        int q = (blockIdx.y * 16 + blockIdx.x) * 256 + tid;   // 0..65535
        if (q < 49152) {
            int m = q >> 14, rem = q & 16383, fp = rem >> 7, f = rem & 127;
            const float* W = (m == 0) ? W0 : (m == 1) ? W1 : W2;
            Wt[q] = f2bf(W[(size_t)f * 128 + fp]);
        } else {
            int u = q - 49152;                    // 0..16383, 8 float4 each
#pragma unroll
            for (int p = 0; p < 8; p++) {
                size_t i4 = (size_t)u + (size_t)p * 16384;
                float4 v = *(const float4*)&X[i4 * 4];
                us4 o; o[0] = f2bf(v.x); o[1] = f2bf(v.y); o[2] = f2bf(v.z); o[3] = f2bf(v.w);
                *(us4*)&Xbf[i4 * 4] = o;
            }
        }
        return;
    }
    int b = blockIdx.z, i0 = blockIdx.y * 64, j0 = blockIdx.x * 64;
    __shared__ float hi[64][FOBS + 1];
    __shared__ float hj[64][FOBS + 1];
    __shared__ float av[FOBS];
    __shared__ float part_s[64][16];
    const float* Xb = X + (size_t)b * NN * FF;
    if (j0 == 0) {                                // Xo passthrough for this row-panel
#pragma unroll
        for (int p = 0; p < 8; p++) {
            int c = p * 256 + tid, r = c >> 5, qq = c & 31;
            *(float4*)&Xo[((size_t)b * NN + i0 + r) * FF + qq * 4] =
                *(const float4*)&Xb[(size_t)(i0 + r) * FF + qq * 4];
        }
    }
#pragma unroll
    for (int l = 0; l < 8; l++) {
        int idx = l * 256 + tid;
        int r = idx >> 5, f = idx & 31;
        hi[r][f] = Xb[(size_t)(i0 + r) * FF + f];
        hj[r][f] = Xb[(size_t)(j0 + r) * FF + f];
    }
    if (tid < FOBS) av[tid] = a_link[tid];
    __syncthreads();

    int ty = tid >> 4, tx = tid & 15;
    int ir = ty * 4, jc = tx * 4;
    float acc[4][4] = {};
#pragma unroll
    for (int f = 0; f < FOBS; f++) {
        float a = av[f];
        float x[4], y[4];
#pragma unroll
        for (int r = 0; r < 4; r++) x[r] = hi[ir + r][f];
#pragma unroll
        for (int c = 0; c < 4; c++) y[c] = hj[jc + c][f];
#pragma unroll
        for (int r = 0; r < 4; r++)
#pragma unroll
            for (int c = 0; c < 4; c++)
                acc[r][c] += fabsf(x[r] - y[c]) * a;
    }
    float* Ab = A + (size_t)b * NN * NN;
    unsigned short* Abb = Abf + (size_t)b * NN * NN;
#pragma unroll
    for (int r = 0; r < 4; r++) {
        int gi = i0 + ir + r;
        float vv[4];
        float rs = 0.f;
#pragma unroll
        for (int c = 0; c < 4; c++) {
            int gj = j0 + jc + c;
            float sg = 1.f / (1.f + __expf(-acc[r][c]));
            vv[c] = (gi == gj) ? 0.f : sg;
            rs += vv[c];
        }
        *(float4*)&Ab[(size_t)gi * NN + (j0 + jc)] = make_float4(vv[0], vv[1], vv[2], vv[3]);
        us4 o; o[0] = f2bf(vv[0]); o[1] = f2bf(vv[1]); o[2] = f2bf(vv[2]); o[3] = f2bf(vv[3]);
        *(us4*)&Abb[(size_t)gi * NN + (j0 + jc)] = o;
        part_s[ir + r][tx] = rs;                  // each (row, tx) slot written once
    }
    __syncthreads();
    if (tid < 64) {                               // 16 partials -> one f32 per row
        float s = 0.f;
#pragma unroll
        for (int k = 0; k < 16; k++) s += part_s[tid][k];
        Pp[((size_t)b * NN + i0 + tid) * 16 + blockIdx.x] = s;
    }
}

// ---------------------------------------------------------------- gw0 (MFMA, 16-node panels)
// Tt[f'][n] = dinv[n] * sum_f Wt0[f'][f] * Xbf[n][f]
__global__ __launch_bounds__(256) void gw0_kernel(const unsigned short* __restrict__ Xbf,
                                                  const unsigned short* __restrict__ Wt0,
                                                  const float* __restrict__ Pp,
                                                  unsigned short* __restrict__ TtOut) {
    int b = blockIdx.y;
    int n0 = blockIdx.x * 16;
    __shared__ unsigned short Wt_s[128 * 128];
    __shared__ unsigned short H_s[16 * 128];
    __shared__ float dinv_s[16];
    int tid = threadIdx.x;
    compute_dinv16(Pp, b, n0, tid, dinv_s);
    const unsigned short* Hb = Xbf + (size_t)b * NN * DD;
#pragma unroll
    for (int p = 0; p < 8; p++) {                 // Wt: 2048 chunks
        int c = p * 256 + tid, row = c >> 4, kc = c & 15;
        gload16(Wt0 + (size_t)row * 128 + ((kc ^ (row & 7)) * 8), Wt_s + (size_t)c * 8);
    }
    {                                             // H tile 16x128: 256 chunks
        int c = tid, row = c >> 4, kc = c & 15;
        gload16(Hb + (size_t)(n0 + row) * 128 + ((kc ^ (row & 7)) * 8), H_s + (size_t)c * 8);
    }
    __syncthreads();

    int w = tid >> 6, l = tid & 63, lr = l & 15, lg = l >> 4;
    ffrag acc[2] = {};
#pragma unroll
    for (int ks = 0; ks < 4; ks++) {
        int k0 = ks * 32 + lg * 8;
        bfrag a[2], bb;
#pragma unroll
        for (int rb = 0; rb < 2; rb++) {
            int row = w * 32 + rb * 16 + lr;
            int byt = (row * 256 + k0 * 2) ^ ((row & 7) << 4);
            a[rb] = *(const bfrag*)((const char*)Wt_s + byt);
        }
        {
            int row = lr;
            int byt = (row * 256 + k0 * 2) ^ ((row & 7) << 4);
            bb = *(const bfrag*)((const char*)H_s + byt);
        }
#pragma unroll
        for (int rb = 0; rb < 2; rb++)
            acc[rb] = __builtin_amdgcn_mfma_f32_16x16x32_bf16(a[rb], bb, acc[rb], 0, 0, 0);
    }
    unsigned short* Ttb = TtOut + (size_t)b * DD * NN;
    int nl = lr;
    float dv = dinv_s[nl];
#pragma unroll
    for (int rb = 0; rb < 2; rb++)
#pragma unroll
        for (int r = 0; r < 4; r++) {
            int f = w * 32 + rb * 16 + lg * 4 + r;
            Ttb[(size_t)f * NN + n0 + nl] = f2bf(acc[rb][r] * dv);
        }
}

// ---------------------------------------------------------------- ga (MFMA, depth-3 pipeline, 16-node panels)
// Dacc[f][n] = sum_k Tt[f][k] * A[k][n] (A symmetric -> read A[n][k] rows contiguous)
// H[n][f] = dinv[n]*(Dacc + Tt[f][n]).
// MODE 0: TtN[f2][n] = dinv[n] * sum_f WtN[f2][f]*H[n][f]; MODE 1: Hs = relu(H) f32.
template <int MODE>
__global__ __launch_bounds__(256) void ga_kernel(const unsigned short* __restrict__ Abf,
                                                 const unsigned short* __restrict__ Tt,
                                                 const unsigned short* __restrict__ WtN,
                                                 const float* __restrict__ Pp,
                                                 unsigned short* __restrict__ TtN,
                                                 float* __restrict__ HsF) {
    int b = blockIdx.y, n0 = blockIdx.x * 16;
    __shared__ unsigned short T_s[3 * 128 * 64];
    __shared__ unsigned short A_s[3 * 16 * 64];
    __shared__ unsigned short W_s[MODE == 0 ? 128 * 128 : 64];
    __shared__ float dinv_s[16];
    int tid = threadIdx.x;
    const unsigned short* Ttb = Tt + (size_t)b * DD * NN;
    const unsigned short* Ab = Abf + (size_t)b * NN * NN;

    compute_dinv16(Pp, b, n0, tid, dinv_s);       // fully drains its own tiny load

    if (MODE == 0) {                              // W for fused epilogue: issued first
#pragma unroll
        for (int p = 0; p < 8; p++) {
            int c = p * 256 + tid, row = c >> 4, kc = c & 15;
            gload16(WtN + (size_t)row * 128 + ((kc ^ (row & 7)) * 8), W_s + (size_t)c * 8);
        }
    }
    auto stageT = [&](int buf, int kt) {          // uniform 5 gload16 per thread
#pragma unroll
        for (int p = 0; p < 4; p++) {
            int c = p * 256 + tid, row = c >> 3, kc = c & 7;
            gload16(Ttb + (size_t)row * NN + kt + ((kc ^ (row & 7)) * 8),
                    T_s + (size_t)buf * (128 * 64) + (size_t)c * 8);
        }
        // A tile 16x64 = 128 chunks; tid>=128 duplicates (same src -> same dest, benign)
        int c = tid & 127, row = c >> 3, kc = c & 7;
        gload16(Ab + (size_t)(n0 + row) * NN + kt + ((kc ^ (row & 7)) * 8),
                A_s + (size_t)buf * (16 * 64) + (size_t)c * 8);
    };
    stageT(0, 0);
    stageT(1, 64);

    int w = tid >> 6, l = tid & 63, lr = l & 15, lg = l >> 4;
    ffrag acc[2] = {};
    int cur = 0, sb = 2;
    for (int t = 0; t < 16; t++) {
        if (t <= 13) stageT(sb, (t + 2) * 64);
        if (t < 14)       asm volatile("s_waitcnt vmcnt(10)" ::: "memory");
        else if (t == 14) asm volatile("s_waitcnt vmcnt(5)"  ::: "memory");
        else              asm volatile("s_waitcnt vmcnt(0)"  ::: "memory");
        __builtin_amdgcn_s_barrier();
        asm volatile("" ::: "memory");
        const unsigned short* Tc = T_s + (size_t)cur * (128 * 64);
        const unsigned short* Ac = A_s + (size_t)cur * (16 * 64);
#pragma unroll
        for (int ks = 0; ks < 2; ks++) {
            int k0 = ks * 32 + lg * 8;
            bfrag a[2], bb;
#pragma unroll
            for (int rb = 0; rb < 2; rb++) {
                int row = w * 32 + rb * 16 + lr;
                int byt = (row * 128 + k0 * 2) ^ ((row & 7) << 4);
                a[rb] = *(const bfrag*)((const char*)Tc + byt);
            }
            {
                int row = lr;
                int byt = (row * 128 + k0 * 2) ^ ((row & 7) << 4);
                bb = *(const bfrag*)((const char*)Ac + byt);
            }
#pragma unroll
            for (int rb = 0; rb < 2; rb++)
                acc[rb] = __builtin_amdgcn_mfma_f32_16x16x32_bf16(a[rb], bb, acc[rb], 0, 0, 0);
        }
        asm volatile("s_waitcnt lgkmcnt(0)" ::: "memory");
        __builtin_amdgcn_s_barrier();             // all reads of buf done before overwrite
        cur = (cur == 2) ? 0 : cur + 1;
        sb = (sb == 2) ? 0 : sb + 1;
    }

    int nl = lr;
    float dv = dinv_s[nl];
    if (MODE == 1) {                              // final: relu, f32, node-major
#pragma unroll
        for (int rb = 0; rb < 2; rb++) {
            int f0 = w * 32 + rb * 16 + lg * 4;
            float v[4];
#pragma unroll
            for (int r = 0; r < 4; r++) {
                float idv = bf2f(Ttb[(size_t)(f0 + r) * NN + n0 + nl]);
                v[r] = fmaxf((acc[rb][r] + idv) * dv, 0.f);
            }
            *(float4*)&HsF[((size_t)b * NN + n0 + nl) * DD + f0] = make_float4(v[0], v[1], v[2], v[3]);
        }
        return;
    }
    // MODE 0: H -> LDS (reuse T_s buffer 0; all pipeline reads done), then @ WtN
    unsigned short* H_s = T_s;                    // [16][128] swizzled, row stride 256B
#pragma unroll
    for (int rb = 0; rb < 2; rb++) {
        int f0 = w * 32 + rb * 16 + lg * 4;
        us4 o;
#pragma unroll
        for (int r = 0; r < 4; r++) {
            float idv = bf2f(Ttb[(size_t)(f0 + r) * NN + n0 + nl]);
            o[r] = f2bf((acc[rb][r] + idv) * dv);
        }
        int byt = (nl * 256 + f0 * 2) ^ ((nl & 7) << 4);
        *(us4*)((char*)H_s + byt) = o;
    }
    __syncthreads();
    ffrag acc2[2] = {};
#pragma unroll
    for (int ks = 0; ks < 4; ks++) {
        int k0 = ks * 32 + lg * 8;
        bfrag a2[2], b2;
#pragma unroll
        for (int rb = 0; rb < 2; rb++) {
            int row = w * 32 + rb * 16 + lr;
            int byt = (row * 256 + k0 * 2) ^ ((row & 7) << 4);
            a2[rb] = *(const bfrag*)((const char*)W_s + byt);
        }
        {
            int row = lr;
            int byt = (row * 256 + k0 * 2) ^ ((row & 7) << 4);
            b2 = *(const bfrag*)((const char*)H_s + byt);
        }
#pragma unroll
        for (int rb = 0; rb < 2; rb++)
            acc2[rb] = __builtin_amdgcn_mfma_f32_16x16x32_bf16(a2[rb], b2, acc2[rb], 0, 0, 0);
    }
    unsigned short* TtNb = TtN + (size_t)b * DD * NN;
#pragma unroll
    for (int rb = 0; rb < 2; rb++)
#pragma unroll
        for (int r = 0; r < 4; r++) {
            int f2 = w * 32 + rb * 16 + lg * 4 + r;
            TtNb[(size_t)f2 * NN + n0 + nl] = f2bf(acc2[rb][r] * dv);
        }
}

// ---------------------------------------------------------------- launcher
extern "C" void kernel_launch(void* const* d_in, const int* in_sizes, int n_in,
                              void* d_out, int out_size, void* d_ws, size_t ws_size,
                              hipStream_t stream) {
    const float* X      = (const float*)d_in[0];
    const float* a_link = (const float*)d_in[1];
    const float* W0     = (const float*)d_in[2];
    const float* W1     = (const float*)d_in[3];
    const float* W2     = (const float*)d_in[4];
    float* out = (float*)d_out;

    const size_t HND = (size_t)BB * NN * DD;     // 524288
    const size_t HNN = (size_t)BB * NN * NN;     // 4194304
    float* Hs = out;
    float* As = out + HND;
    float* Xo = out + HND + HNN;
    float* Ds = out + 2 * HND + HNN;

    // scratch layout (bytes): Abf 8388608 | Xbf 1048576 | TtA 1048576 | TtB 1048576
    //                         | Wt 98304 | Pp 262144  => total 11894784
    const size_t NEED = 11894784;
    bool usews = (ws_size >= NEED);
    char* scr = usews ? (char*)d_ws : (char*)Ds;

    unsigned short* Abf = (unsigned short*)(scr);
    unsigned short* Xbf = (unsigned short*)(scr + 8388608);
    unsigned short* TtA = (unsigned short*)(scr + 9437184);
    unsigned short* TtB = (unsigned short*)(scr + 10485760);
    unsigned short* Wt  = (unsigned short*)(scr + 11534336);
    float* Pp           = (float*)(scr + 11632640);

    adj_kernel<<<dim3(16, 16, usews ? 6 : 5), 256, 0, stream>>>(
        X, a_link, W0, W1, W2, As, Abf, Xbf, Wt, Pp, Xo, usews ? Ds : nullptr);

    gw0_kernel<<<dim3(64, BB), 256, 0, stream>>>(Xbf, Wt, Pp, TtA);
    ga_kernel<0><<<dim3(64, BB), 256, 0, stream>>>(Abf, TtA, Wt + 16384, Pp, TtB, nullptr);
    ga_kernel<0><<<dim3(64, BB), 256, 0, stream>>>(Abf, TtB, Wt + 32768, Pp, TtA, nullptr);
    ga_kernel<1><<<dim3(64, BB), 256, 0, stream>>>(Abf, TtA, nullptr, Pp, nullptr, Hs);

    if (!usews)                                   // scratch lived in Ds: zero it now
        zero_f4<<<dim3(4096), 256, 0, stream>>>((float4*)Ds, (int)(HNN / 4));
}